// Round 6
// baseline (135.161 us; speedup 1.0000x reference)
//
#include <hip/hip_runtime.h>
#include <hip/hip_bf16.h>

// Problem dims (fixed by setup_inputs): B=16, A=9, H=56, W=56, N=64.
// Output: (B, A*H*W, N) fp32 IoU matrix.
//
// R5: software-pipelined multi-chunk blocks.
//   Each block owns 3 chunks of 192 proposals (one batch per block; 147
//   chunks/batch = 49 blocks x 3). Double-buffered LDS box cache: global
//   loads for chunk c+1 are issued BEFORE the store loop of chunk c, so
//   HBM read latency and exp-decode hide behind the 48KB store stream,
//   and waves live 3x longer issuing stores (fixes the load->barrier->
//   short-store-burst convoy of R4).
//   Store mapping per wave (as R4): lane L -> proposal sub-index q=L>>4,
//   bbox group g=L&15; one ds_read_b128 (16-way broadcast) + one
//   global_store_dwordx4 per iteration -> contiguous 1KB per wave-inst.

constexpr int B_ = 16;
constexpr int A_ = 9;
constexpr int H_ = 56;
constexpr int W_ = 56;
constexpr int N_ = 64;
constexpr int HW_ = H_ * W_;            // 3136
constexpr int P_ = A_ * HW_;            // 28224 proposals per batch
constexpr int BLOCK = 192;              // 3 waves
constexpr int CPB = 3;                  // chunks per block
constexpr int BLKS_PER_BATCH = P_ / (BLOCK * CPB);  // 49

typedef float floatx4 __attribute__((ext_vector_type(4)));

__global__ __launch_bounds__(BLOCK) void ssd_iou_kernel(
    const float* __restrict__ anc,      // (A,2)
    const float* __restrict__ grid,     // (B,H,W,2)
    const float* __restrict__ offsets,  // (B,A,H,W,4)
    const float* __restrict__ bboxes,   // (B,N,5)
    float* __restrict__ out)            // (B, P, N)
{
    __shared__ float4 s_box[2][BLOCK];

    const int t   = threadIdx.x;
    const int b   = blockIdx.x / BLKS_PER_BATCH;          // batch (uniform)
    const int blk = blockIdx.x - b * BLKS_PER_BATCH;      // block within batch
    const int lp0 = blk * (BLOCK * CPB);                  // first local proposal

    // ---- fetch: issue global loads for one proposal (no use yet) ----
    auto fetch = [&](int lp, float4& off, float2& g, float& aw, float& ah) {
        const int a  = lp / HW_;
        const int hw = lp - a * HW_;
        off = reinterpret_cast<const float4*>(offsets)[b * P_ + lp];
        g   = reinterpret_cast<const float2*>(grid)[b * HW_ + hw];
        aw  = anc[2 * a + 0];
        ah  = anc[2 * a + 1];
    };
    // ---- decode: consume loads, write box to LDS buffer ----
    auto decode = [&](int buf, const float4& off, const float2& g,
                      float aw, float ah) {
        const float xc = g.x + off.x;
        const float yc = g.y + off.y;
        const float wp = aw * __expf(off.z);
        const float hp = ah * __expf(off.w);
        float4 box;
        box.x = xc - 0.5f * wp;
        box.y = yc - 0.5f * hp;
        box.z = xc + 0.5f * wp;
        box.w = yc + 0.5f * hp;
        s_box[buf][t] = box;
    };

    // Per-lane bbox constants (4 boxes). 20KB total -> L1/L2-resident.
    const int wave = t >> 6;
    const int lane = t & 63;
    const int q    = lane >> 4;   // proposal sub-index within group of 4
    const int g16  = lane & 15;   // bbox group: bboxes 4g..4g+3

    float bx0[4], by0[4], bx1[4], by1[4], aob[4];
    #pragma unroll
    for (int k = 0; k < 4; ++k) {
        const float* bb = bboxes + ((size_t)(b * N_ + 4 * g16 + k)) * 5;
        bx0[k] = bb[0];
        by0[k] = bb[1];
        bx1[k] = bb[2];
        by1[k] = bb[3];
        aob[k] = (bx1[k] - bx0[k]) * (by1[k] - by0[k]);
    }

    // Prologue: chunk 0 into buffer 0.
    float4 off; float2 g; float aw, ah;
    fetch(lp0 + t, off, g, aw, ah);
    decode(0, off, g, aw, ah);
    __syncthreads();

    for (int c = 0; c < CPB; ++c) {
        // Issue next chunk's global loads before the store stream.
        if (c + 1 < CPB)
            fetch(lp0 + (c + 1) * BLOCK + t, off, g, aw, ah);

        const float4* sb = &s_box[c & 1][wave * 64];
        float* obase = out
            + ((size_t)(b * P_ + lp0 + c * BLOCK + wave * 64 + q)) * N_
            + 4 * g16;

        #pragma unroll
        for (int j = 0; j < 16; ++j) {
            const float4 pr = sb[4 * j + q];
            const float aop = (pr.z - pr.x) * (pr.w - pr.y);

            floatx4 res;
            #pragma unroll
            for (int k = 0; k < 4; ++k) {
                const float tlx = fmaxf(pr.x, bx0[k]);
                const float tly = fmaxf(pr.y, by0[k]);
                const float brx = fminf(pr.z, bx1[k]);
                const float bry = fminf(pr.w, by1[k]);

                const float iw  = fmaxf(brx - tlx, 0.0f);
                const float ih  = fmaxf(bry - tly, 0.0f);
                const float aoi = iw * ih;

                const float denom = aop + aob[k] - aoi;
                res[k] = aoi * __builtin_amdgcn_rcpf(denom);
            }

            *reinterpret_cast<floatx4*>(obase + (size_t)(4 * j) * N_) = res;
        }

        // Decode next chunk into the other buffer, then sync.
        if (c + 1 < CPB)
            decode((c + 1) & 1, off, g, aw, ah);
        __syncthreads();
    }
}

extern "C" void kernel_launch(void* const* d_in, const int* in_sizes, int n_in,
                              void* d_out, int out_size, void* d_ws, size_t ws_size,
                              hipStream_t stream) {
    const float* anc     = (const float*)d_in[0];
    const float* grid    = (const float*)d_in[1];
    const float* offsets = (const float*)d_in[2];
    const float* bboxes  = (const float*)d_in[3];
    float* out = (float*)d_out;

    const int nblocks = B_ * BLKS_PER_BATCH;   // 784
    ssd_iou_kernel<<<nblocks, BLOCK, 0, stream>>>(anc, grid, offsets, bboxes, out);
}

// Round 7
// 130.553 us; speedup vs baseline: 1.0353x; 1.0353x over previous
//
#include <hip/hip_runtime.h>
#include <hip/hip_bf16.h>

// Problem dims (fixed by setup_inputs): B=16, A=9, H=56, W=56, N=64.
// Output: (B, A*H*W, N) fp32 IoU matrix.
//
// R6: barrier-free, LDS-free "fill-alike" kernel.
//   One wave per 64 consecutive proposals (441 waves/batch exactly; waves
//   never straddle a batch). Each lane decodes its OWN proposal into regs
//   (coalesced float4/float2 loads, 2x __expf). The proposal->row transpose
//   is done with __shfl (ds_bpermute: crosslane only, no LDS storage, no
//   __syncthreads anywhere).
//   Store loop: lane L -> row sub-index q=L>>4, bbox group g=L&15.
//   Iter j broadcasts boxes of proposals 4j..4j+3 via 4 shfls (one shared
//   index), computes 4 IoUs/lane, and issues one global_store_dwordx4 ->
//   contiguous 1KB per wave-inst; each wave streams 16KB linear.
//   No barriers => every wave is an independent store stream; late waves'
//   loads overlap early waves' stores (same structure as the 6.5TB/s fill).

constexpr int B_ = 16;
constexpr int A_ = 9;
constexpr int H_ = 56;
constexpr int W_ = 56;
constexpr int N_ = 64;
constexpr int HW_ = H_ * W_;            // 3136
constexpr int P_ = A_ * HW_;            // 28224 proposals per batch
constexpr int WPB = P_ / 64;            // 441 waves per batch
constexpr int NWAVES = B_ * WPB;        // 7056
constexpr int BLOCK = 256;

typedef float floatx4 __attribute__((ext_vector_type(4)));

__global__ __launch_bounds__(BLOCK) void ssd_iou_kernel(
    const float* __restrict__ anc,      // (A,2)
    const float* __restrict__ grid,     // (B,H,W,2)
    const float* __restrict__ offsets,  // (B,A,H,W,4)
    const float* __restrict__ bboxes,   // (B,N,5)
    float* __restrict__ out)            // (B, P, N)
{
    const int t    = blockIdx.x * BLOCK + threadIdx.x;
    const int w    = t >> 6;            // global wave id, 0..7055
    const int lane = t & 63;

    const int b  = w / WPB;             // batch (wave-uniform)
    const int lp = (w - b * WPB) * 64 + lane;   // this lane's local proposal

    // ---- decode own proposal into registers ----
    const int a  = lp / HW_;
    const int hw = lp - a * HW_;

    const float4 off = reinterpret_cast<const float4*>(offsets)[b * P_ + lp];
    const float2 g   = reinterpret_cast<const float2*>(grid)[b * HW_ + hw];
    const float  aw  = anc[2 * a + 0];
    const float  ah  = anc[2 * a + 1];

    const float xc = g.x + off.x;
    const float yc = g.y + off.y;
    const float wp = aw * __expf(off.z);
    const float hp = ah * __expf(off.w);

    const float mx0 = xc - 0.5f * wp;   // own box
    const float my0 = yc - 0.5f * hp;
    const float mx1 = xc + 0.5f * wp;
    const float my1 = yc + 0.5f * hp;

    // ---- per-lane bbox constants (4 boxes; 20KB total -> L1-resident) ----
    const int q   = lane >> 4;          // row sub-index within group of 4
    const int g16 = lane & 15;          // bbox group: bboxes 4g..4g+3

    float bx0[4], by0[4], bx1[4], by1[4], aob[4];
    #pragma unroll
    for (int k = 0; k < 4; ++k) {
        const float* bb = bboxes + ((size_t)(b * N_ + 4 * g16 + k)) * 5;
        bx0[k] = bb[0];
        by0[k] = bb[1];
        bx1[k] = bb[2];
        by1[k] = bb[3];
        aob[k] = (bx1[k] - bx0[k]) * (by1[k] - by0[k]);
    }

    // out rows for this wave start at proposal w*64; wave writes 16KB linear.
    float* obase = out + (size_t)w * (64 * N_) + q * N_ + 4 * g16;

    #pragma unroll
    for (int j = 0; j < 16; ++j) {
        const int src = 4 * j + q;      // proposal lane to broadcast
        const float px0 = __shfl(mx0, src);
        const float py0 = __shfl(my0, src);
        const float px1 = __shfl(mx1, src);
        const float py1 = __shfl(my1, src);
        const float aop = (px1 - px0) * (py1 - py0);

        floatx4 res;
        #pragma unroll
        for (int k = 0; k < 4; ++k) {
            const float tlx = fmaxf(px0, bx0[k]);
            const float tly = fmaxf(py0, by0[k]);
            const float brx = fminf(px1, bx1[k]);
            const float bry = fminf(py1, by1[k]);

            const float iw  = fmaxf(brx - tlx, 0.0f);
            const float ih  = fmaxf(bry - tly, 0.0f);
            const float aoi = iw * ih;

            const float denom = aop + aob[k] - aoi;
            res[k] = aoi * __builtin_amdgcn_rcpf(denom);
        }

        *reinterpret_cast<floatx4*>(obase + (size_t)j * (4 * N_)) = res;
    }
}

extern "C" void kernel_launch(void* const* d_in, const int* in_sizes, int n_in,
                              void* d_out, int out_size, void* d_ws, size_t ws_size,
                              hipStream_t stream) {
    const float* anc     = (const float*)d_in[0];
    const float* grid    = (const float*)d_in[1];
    const float* offsets = (const float*)d_in[2];
    const float* bboxes  = (const float*)d_in[3];
    float* out = (float*)d_out;

    const int nblocks = (NWAVES * 64) / BLOCK;   // 1764
    ssd_iou_kernel<<<nblocks, BLOCK, 0, stream>>>(anc, grid, offsets, bboxes, out);
}